// Round 1
// baseline (2826.681 us; speedup 1.0000x reference)
//
#include <hip/hip_runtime.h>

#define FIN 256
#define HID 64
#define NLAYERS 5

__global__ __launch_bounds__(256) void k_deg(const int* __restrict__ src, const int* __restrict__ dst,
                                             float* __restrict__ degs, float* __restrict__ degd, int E) {
  int i = blockIdx.x * 256 + threadIdx.x;
  if (i < E) {
    atomicAdd(&degs[src[i]], 1.0f);
    atomicAdd(&degd[dst[i]], 1.0f);
  }
}

__global__ __launch_bounds__(256) void k_norm(float* __restrict__ buf, int n) {
  int i = blockIdx.x * 256 + threadIdx.x;
  if (i < n) buf[i] = rsqrtf(fmaxf(buf[i], 1.0f));
}

// hs[row][j] = ns[row] * sum_k feats[row][k] * W0[k][j]
__global__ __launch_bounds__(256) void k_gemm0(const float* __restrict__ feats, const float* __restrict__ ns,
                                               const float* __restrict__ W0, float* __restrict__ hs, int nrows) {
  __shared__ float sW[128 * HID];   // 32 KB: half of K at a time
  __shared__ float sh[16][FIN];     // 16 KB: 16 rows of feats
  const int tid = threadIdx.x;
  const int row0 = blockIdx.x * 16;
  for (int t = tid; t < 16 * FIN; t += 256) {
    int r = t >> 8, c = t & 255;
    int rr = row0 + r;
    sh[r][c] = (rr < nrows) ? feats[(size_t)rr * FIN + c] : 0.0f;
  }
  const int j = tid & 63;       // output column (lane)
  const int rq = tid >> 6;      // wave id -> row quad
  float acc[4] = {0.f, 0.f, 0.f, 0.f};
  for (int kb = 0; kb < FIN; kb += 128) {
    __syncthreads();
    for (int t = tid; t < 128 * HID; t += 256) sW[t] = W0[kb * HID + t];
    __syncthreads();
    for (int k = 0; k < 128; ++k) {
      float w = sW[k * HID + j];              // 2-way bank alias: free
      #pragma unroll
      for (int r = 0; r < 4; ++r) acc[r] += sh[rq * 4 + r][kb + k] * w;  // wave-uniform broadcast
    }
  }
  #pragma unroll
  for (int r = 0; r < 4; ++r) {
    int row = row0 + rq * 4 + r;
    if (row < nrows) hs[(size_t)row * HID + j] = acc[r] * ns[row];
  }
}

// y[dst[e]][f] += x[src[e]][f]  over all (e, f)
__global__ __launch_bounds__(256) void k_scatter(const int* __restrict__ src, const int* __restrict__ dst,
                                                 const float* __restrict__ x, float* __restrict__ y,
                                                 long long total) {
  long long stride = (long long)gridDim.x * 256;
  for (long long i = (long long)blockIdx.x * 256 + threadIdx.x; i < total; i += stride) {
    int e = (int)(i >> 6);
    int f = (int)(i & 63);
    int s = src[e], d = dst[e];
    atomicAdd(&y[(size_t)d * HID + f], x[(size_t)s * HID + f]);
  }
}

__global__ __launch_bounds__(256) void k_relu(const float* __restrict__ agg, const float* __restrict__ nd,
                                              const float* __restrict__ b, float* __restrict__ h, int n64) {
  int i = blockIdx.x * 256 + threadIdx.x;
  if (i < n64) {
    float v = agg[i] * nd[i >> 6] + b[i & 63];
    h[i] = v > 0.0f ? v : 0.0f;
  }
}

// If W != null: hs[row][j] = ns[row] * sum_k h[row][k]*W[k][j]
// Always:       proj[row][j] += sum_k h[row][k]*Wb[k][j]   (unnormalized, for final JK projection)
__global__ __launch_bounds__(256) void k_gemm_dual(const float* __restrict__ h, const float* __restrict__ ns,
                                                   const float* __restrict__ W, const float* __restrict__ Wb,
                                                   float* __restrict__ hs, float* __restrict__ proj, int nrows) {
  __shared__ float sW[HID * HID];    // 16 KB
  __shared__ float sWb[HID * HID];   // 16 KB
  __shared__ float sh[4][HID];
  const int tid = threadIdx.x;
  const bool hasW = (W != nullptr);
  for (int t = tid; t < HID * HID; t += 256) {
    if (hasW) sW[t] = W[t];
    sWb[t] = Wb[t];
  }
  const int row0 = blockIdx.x * 16;
  const int r = tid >> 6, j = tid & 63;
  for (int g = 0; g < 4; ++g) {
    int row = row0 + g * 4 + r;
    __syncthreads();
    sh[r][j] = (row < nrows) ? h[(size_t)row * HID + j] : 0.0f;
    __syncthreads();
    float accB = 0.0f;
    if (hasW) {
      float accW = 0.0f;
      #pragma unroll
      for (int k = 0; k < HID; ++k) {
        float a = sh[r][k];              // wave-uniform broadcast
        accW += a * sW[k * HID + j];
        accB += a * sWb[k * HID + j];
      }
      if (row < nrows) hs[(size_t)row * HID + j] = accW * ns[row];
    } else {
      #pragma unroll
      for (int k = 0; k < HID; ++k) accB += sh[r][k] * sWb[k * HID + j];
    }
    if (row < nrows) proj[(size_t)row * HID + j] += accB;
  }
}

__global__ __launch_bounds__(256) void k_bias(float* __restrict__ out, const float* __restrict__ bout, int n64) {
  int i = blockIdx.x * 256 + threadIdx.x;
  if (i < n64) out[i] += bout[i & 63];
}

extern "C" void kernel_launch(void* const* d_in, const int* in_sizes, int n_in,
                              void* d_out, int out_size, void* d_ws, size_t ws_size,
                              hipStream_t stream) {
  const float* feats = (const float*)d_in[0];
  const int* src = (const int*)d_in[1];
  const int* dst = (const int*)d_in[2];
  const float* W[NLAYERS]    = {(const float*)d_in[3], (const float*)d_in[5], (const float*)d_in[7],
                                (const float*)d_in[9], (const float*)d_in[11]};
  const float* bias[NLAYERS] = {(const float*)d_in[4], (const float*)d_in[6], (const float*)d_in[8],
                                (const float*)d_in[10], (const float*)d_in[12]};
  const float* Wout = (const float*)d_in[13];
  const float* bout = (const float*)d_in[14];
  float* out = (float*)d_out;

  const int N = in_sizes[0] / FIN;
  const int E = in_sizes[1];

  // Workspace layout (floats): norm_s[N] | norm_d[N] | h[N*64] | hs[N*64] | agg[N*64] | proj[N*64]
  float* ws = (float*)d_ws;
  float* norm_s = ws;                        // also accumulates out-degree
  float* norm_d = ws + N;                    // also accumulates in-degree
  float* h      = ws + 2 * (size_t)N;
  float* hsbuf  = h + (size_t)N * HID;
  float* agg    = hsbuf + (size_t)N * HID;
  float* proj   = agg + (size_t)N * HID;

  hipMemsetAsync(norm_s, 0, (size_t)2 * N * sizeof(float), stream);
  hipMemsetAsync(proj, 0, (size_t)N * HID * sizeof(float), stream);
  hipMemsetAsync(out, 0, (size_t)N * HID * sizeof(float), stream);

  k_deg<<<(E + 255) / 256, 256, 0, stream>>>(src, dst, norm_s, norm_d, E);
  k_norm<<<(2 * N + 255) / 256, 256, 0, stream>>>(norm_s, 2 * N);   // norm_s/norm_d contiguous
  k_gemm0<<<(N + 15) / 16, 256, 0, stream>>>(feats, norm_s, W[0], hsbuf, N);

  const long long totE = (long long)E * HID;
  const int SC_BLOCKS = 16384;
  for (int i = 0; i < NLAYERS; ++i) {
    hipMemsetAsync(agg, 0, (size_t)N * HID * sizeof(float), stream);
    k_scatter<<<SC_BLOCKS, 256, 0, stream>>>(src, dst, hsbuf, agg, totE);
    k_relu<<<(N * HID + 255) / 256, 256, 0, stream>>>(agg, norm_d, bias[i], h, N * HID);
    const float* Wn = (i < NLAYERS - 1) ? W[i + 1] : nullptr;
    k_gemm_dual<<<(N + 15) / 16, 256, 0, stream>>>(h, norm_s, Wn, Wout + (size_t)i * HID * HID,
                                                   hsbuf, proj, N);
  }
  k_scatter<<<SC_BLOCKS, 256, 0, stream>>>(src, dst, proj, out, totE);
  k_bias<<<(N * HID + 255) / 256, 256, 0, stream>>>(out, bout, N * HID);
}

// Round 2
// 1245.523 us; speedup vs baseline: 2.2695x; 2.2695x over previous
//
#include <hip/hip_runtime.h>

#define FIN 256
#define HID 64
#define NLAYERS 5

// ---- degree histogram (int) ----
__global__ __launch_bounds__(256) void k_deg_i(const int* __restrict__ src, const int* __restrict__ dst,
                                               int* __restrict__ cs, int* __restrict__ cd, int E) {
  int i = blockIdx.x * 256 + threadIdx.x;
  if (i < E) {
    atomicAdd(&cs[src[i]], 1);
    atomicAdd(&cd[dst[i]], 1);
  }
}

__global__ __launch_bounds__(256) void k_norm(const int* __restrict__ cnt, float* __restrict__ nrm, int n) {
  int i = blockIdx.x * 256 + threadIdx.x;
  if (i < n) nrm[i] = rsqrtf(fmaxf((float)cnt[i], 1.0f));
}

// ---- CSR row allocation: wave-level exclusive scan + one atomic per wave ----
__global__ __launch_bounds__(256) void k_rowalloc(const int* __restrict__ cnt, int* __restrict__ row_start,
                                                  int* __restrict__ cursor, int* __restrict__ gcur, int n) {
  int i = blockIdx.x * 256 + threadIdx.x;
  int lane = threadIdx.x & 63;
  int c = (i < n) ? cnt[i] : 0;
  int s = c;                               // inclusive wave scan
  #pragma unroll
  for (int d = 1; d < 64; d <<= 1) {
    int t = __shfl_up(s, d, 64);
    if (lane >= d) s += t;
  }
  int total = __shfl(s, 63, 64);
  int base = 0;
  if (lane == 63) base = atomicAdd(gcur, total);
  base = __shfl(base, 63, 64);
  int start = base + s - c;                // exclusive
  if (i < n) {
    row_start[i] = start;
    cursor[i] = start;
  }
}

__global__ __launch_bounds__(256) void k_fill(const int* __restrict__ src, const int* __restrict__ dst,
                                              int* __restrict__ cursor, int* __restrict__ col, int E) {
  int e = blockIdx.x * 256 + threadIdx.x;
  if (e < E) {
    int pos = atomicAdd(&cursor[dst[e]], 1);
    col[pos] = src[e];
  }
}

// ---- hs[row][j] = ns[row] * sum_k feats[row][k] * W0[k][j] ----
__global__ __launch_bounds__(256) void k_gemm0(const float* __restrict__ feats, const float* __restrict__ ns,
                                               const float* __restrict__ W0, float* __restrict__ hs, int nrows) {
  __shared__ float sW[128 * HID];
  __shared__ float sh[16][FIN];
  const int tid = threadIdx.x;
  const int row0 = blockIdx.x * 16;
  for (int t = tid; t < 16 * FIN; t += 256) {
    int r = t >> 8, c = t & 255;
    int rr = row0 + r;
    sh[r][c] = (rr < nrows) ? feats[(size_t)rr * FIN + c] : 0.0f;
  }
  const int j = tid & 63;
  const int rq = tid >> 6;
  float acc[4] = {0.f, 0.f, 0.f, 0.f};
  for (int kb = 0; kb < FIN; kb += 128) {
    __syncthreads();
    for (int t = tid; t < 128 * HID; t += 256) sW[t] = W0[kb * HID + t];
    __syncthreads();
    for (int k = 0; k < 128; ++k) {
      float w = sW[k * HID + j];
      #pragma unroll
      for (int r = 0; r < 4; ++r) acc[r] += sh[rq * 4 + r][kb + k] * w;
    }
  }
  #pragma unroll
  for (int r = 0; r < 4; ++r) {
    int row = row0 + rq * 4 + r;
    if (row < nrows) hs[(size_t)row * HID + j] = acc[r] * ns[row];
  }
}

// ---- gather-sum over in-edges, fused relu(acc*nd + b) ----
__global__ __launch_bounds__(256) void k_gather_relu(const int* __restrict__ row_start, const int* __restrict__ cnt,
                                                     const int* __restrict__ col, const float* __restrict__ x,
                                                     const float* __restrict__ nd, const float* __restrict__ b,
                                                     float* __restrict__ h, int n) {
  int node = blockIdx.x * 4 + (threadIdx.x >> 6);
  int lane = threadIdx.x & 63;
  if (node >= n) return;
  int j = row_start[node];
  int end = j + cnt[node];
  float acc = 0.f;
  for (; j + 4 <= end; j += 4) {
    int s0 = col[j], s1 = col[j + 1], s2 = col[j + 2], s3 = col[j + 3];
    float v0 = x[(size_t)s0 * HID + lane];
    float v1 = x[(size_t)s1 * HID + lane];
    float v2 = x[(size_t)s2 * HID + lane];
    float v3 = x[(size_t)s3 * HID + lane];
    acc += (v0 + v1) + (v2 + v3);
  }
  for (; j < end; ++j) acc += x[(size_t)col[j] * HID + lane];
  float v = acc * nd[node] + b[lane];
  h[(size_t)node * HID + lane] = fmaxf(v, 0.f);
}

// ---- final gather-sum, fused + bout ----
__global__ __launch_bounds__(256) void k_gather_bias(const int* __restrict__ row_start, const int* __restrict__ cnt,
                                                     const int* __restrict__ col, const float* __restrict__ x,
                                                     const float* __restrict__ bout, float* __restrict__ out, int n) {
  int node = blockIdx.x * 4 + (threadIdx.x >> 6);
  int lane = threadIdx.x & 63;
  if (node >= n) return;
  int j = row_start[node];
  int end = j + cnt[node];
  float acc = 0.f;
  for (; j + 4 <= end; j += 4) {
    int s0 = col[j], s1 = col[j + 1], s2 = col[j + 2], s3 = col[j + 3];
    float v0 = x[(size_t)s0 * HID + lane];
    float v1 = x[(size_t)s1 * HID + lane];
    float v2 = x[(size_t)s2 * HID + lane];
    float v3 = x[(size_t)s3 * HID + lane];
    acc += (v0 + v1) + (v2 + v3);
  }
  for (; j < end; ++j) acc += x[(size_t)col[j] * HID + lane];
  out[(size_t)node * HID + lane] = acc + bout[lane];
}

// ---- dual GEMM: hs = ns*(h@W); proj += h@Wb ----
__global__ __launch_bounds__(256) void k_gemm_dual(const float* __restrict__ h, const float* __restrict__ ns,
                                                   const float* __restrict__ W, const float* __restrict__ Wb,
                                                   float* __restrict__ hs, float* __restrict__ proj, int nrows) {
  __shared__ float sW[HID * HID];
  __shared__ float sWb[HID * HID];
  __shared__ float sh[4][HID];
  const int tid = threadIdx.x;
  const bool hasW = (W != nullptr);
  for (int t = tid; t < HID * HID; t += 256) {
    if (hasW) sW[t] = W[t];
    sWb[t] = Wb[t];
  }
  const int row0 = blockIdx.x * 16;
  const int r = tid >> 6, j = tid & 63;
  for (int g = 0; g < 4; ++g) {
    int row = row0 + g * 4 + r;
    __syncthreads();
    sh[r][j] = (row < nrows) ? h[(size_t)row * HID + j] : 0.0f;
    __syncthreads();
    float accB = 0.0f;
    if (hasW) {
      float accW = 0.0f;
      #pragma unroll
      for (int k = 0; k < HID; ++k) {
        float a = sh[r][k];
        accW += a * sW[k * HID + j];
        accB += a * sWb[k * HID + j];
      }
      if (row < nrows) hs[(size_t)row * HID + j] = accW * ns[row];
    } else {
      #pragma unroll
      for (int k = 0; k < HID; ++k) accB += sh[r][k] * sWb[k * HID + j];
    }
    if (row < nrows) proj[(size_t)row * HID + j] += accB;
  }
}

extern "C" void kernel_launch(void* const* d_in, const int* in_sizes, int n_in,
                              void* d_out, int out_size, void* d_ws, size_t ws_size,
                              hipStream_t stream) {
  const float* feats = (const float*)d_in[0];
  const int* src = (const int*)d_in[1];
  const int* dst = (const int*)d_in[2];
  const float* W[NLAYERS]    = {(const float*)d_in[3], (const float*)d_in[5], (const float*)d_in[7],
                                (const float*)d_in[9], (const float*)d_in[11]};
  const float* bias[NLAYERS] = {(const float*)d_in[4], (const float*)d_in[6], (const float*)d_in[8],
                                (const float*)d_in[10], (const float*)d_in[12]};
  const float* Wout = (const float*)d_in[13];
  const float* bout = (const float*)d_in[14];
  float* out = (float*)d_out;

  const int N = in_sizes[0] / FIN;
  const int E = in_sizes[1];
  const size_t Np = (size_t)((N + 63) / 64) * 64;   // 256B-aligned strides
  const size_t Ep = (size_t)((E + 63) / 64) * 64;

  // ---- workspace layout ----
  char* w = (char*)d_ws;
  int* cnt_s     = (int*)w;            w += Np * 4;
  int* cnt_d     = (int*)w;            w += Np * 4;   // cnt_s,cnt_d contiguous -> single memset
  int* row_start = (int*)w;            w += Np * 4;
  int* cursor    = (int*)w;            w += Np * 4;
  int* gcur      = (int*)w;            w += 64 * 4;
  int* col       = (int*)w;            w += Ep * 4;
  float* norm_s  = (float*)w;          w += Np * 4;
  float* norm_d  = (float*)w;          w += Np * 4;
  float* h       = (float*)w;          w += Np * HID * 4;
  float* hsbuf   = (float*)w;          w += Np * HID * 4;
  float* proj    = (float*)w;          w += Np * HID * 4;

  hipMemsetAsync(cnt_s, 0, 2 * Np * sizeof(int), stream);
  hipMemsetAsync(gcur, 0, sizeof(int), stream);
  hipMemsetAsync(proj, 0, (size_t)N * HID * sizeof(float), stream);

  // ---- CSR build (per call; deterministic work) ----
  k_deg_i<<<(E + 255) / 256, 256, 0, stream>>>(src, dst, cnt_s, cnt_d, E);
  k_norm<<<(N + 255) / 256, 256, 0, stream>>>(cnt_s, norm_s, N);
  k_norm<<<(N + 255) / 256, 256, 0, stream>>>(cnt_d, norm_d, N);
  k_rowalloc<<<(N + 255) / 256, 256, 0, stream>>>(cnt_d, row_start, cursor, gcur, N);
  k_fill<<<(E + 255) / 256, 256, 0, stream>>>(src, dst, cursor, col, E);

  // ---- layers ----
  k_gemm0<<<(N + 15) / 16, 256, 0, stream>>>(feats, norm_s, W[0], hsbuf, N);

  const int GB = (N + 3) / 4;
  for (int i = 0; i < NLAYERS; ++i) {
    k_gather_relu<<<GB, 256, 0, stream>>>(row_start, cnt_d, col, hsbuf, norm_d, bias[i], h, N);
    const float* Wn = (i < NLAYERS - 1) ? W[i + 1] : nullptr;
    k_gemm_dual<<<(N + 15) / 16, 256, 0, stream>>>(h, norm_s, Wn, Wout + (size_t)i * HID * HID,
                                                   hsbuf, proj, N);
  }
  k_gather_bias<<<GB, 256, 0, stream>>>(row_start, cnt_d, col, proj, bout, out, N);
}